// Round 5
// baseline (344.921 us; speedup 1.0000x reference)
//
#include <hip/hip_runtime.h>

// B=64, C=1024, HW=1024. x fp32 [B,C,HW] = 256 MiB = exactly L3 size.
// Two full passes thrash LRU at capacity -> 512 MiB DRAM (measured 82-85us).
// Fix: ONE persistent kernel, batches pipelined in a sliding WINDOW=32.
// Block = (b, chunk of 64 channels) claims work from an atomic queue:
//   gate:  wait flag[b-WINDOW]           (throttle -> reuse distance 128 MiB)
//   score: stream 256 KiB slab (DRAM), write partial scores
//   last-arriver of b: merge 16 partials, softmax, set flag[b]
//   pool:  re-read slab (now L3-HOT), dot with attn, write out[b, chunk]
// Queue claiming keeps lowest ids on resident blocks -> deadlock-free at any
// occupancy. Fixed work partition -> deterministic. Ctrl zeroed via memset
// node each launch (ws not re-poisoned between replays).
#define NB 64
#define NC 1024
#define NHW 1024
#define NCHUNK 16
#define CCH (NC / NCHUNK)     // 64 channels per block
#define WINDOW 32
#define NBLK (NB * NCHUNK)    // 1024 blocks

#define AGENT __HIP_MEMORY_SCOPE_AGENT

__device__ inline float wave_reduce_sum(float v) {
    #pragma unroll
    for (int off = 32; off; off >>= 1) v += __shfl_xor(v, off);
    return v;
}
__device__ inline float wave_reduce_max(float v) {
    #pragma unroll
    for (int off = 32; off; off >>= 1) v = fmaxf(v, __shfl_xor(v, off));
    return v;
}

// ctrl layout (ints): [0] claim ctr | [64..127] score_done[b] | [128..191] flag[b]
__global__ __launch_bounds__(256, 4) void fused_pipeline_kernel(
        const float* __restrict__ x, const float* __restrict__ w,
        float* __restrict__ partials, float* __restrict__ attn,
        int* __restrict__ ctrl, float* __restrict__ out) {
    __shared__ int s_vbid;
    __shared__ int s_last;
    __shared__ float redm[4], reds[4];

    const int tid  = threadIdx.x;
    const int wave = tid >> 6, lane = tid & 63;

    if (tid == 0)
        s_vbid = __hip_atomic_fetch_add(&ctrl[0], 1, __ATOMIC_RELAXED, AGENT);
    __syncthreads();
    const int vbid  = s_vbid;
    const int b     = vbid >> 4;
    const int chunk = vbid & 15;
    const int c0    = chunk * CCH;
    int* score_done = ctrl + 64;
    int* flag       = ctrl + 128;

    // ---- window gate: throttle so pool(b-W) reads x while it's L3-hot ----
    if (b >= WINDOW) {
        if (tid == 0) {
            while (__hip_atomic_load(&flag[b - WINDOW], __ATOMIC_RELAXED, AGENT) == 0)
                __builtin_amdgcn_s_sleep(8);
        }
        __syncthreads();
    }

    // ---- score phase: partial scores from this 256 KiB slab (DRAM) ----
    const float* xb = x + ((size_t)(b * NC + c0)) * NHW + tid * 4;
    float4 ps = {0.f, 0.f, 0.f, 0.f};
    #pragma unroll 8
    for (int k = 0; k < CCH; ++k) {
        const float4 v = *reinterpret_cast<const float4*>(xb + (size_t)k * NHW);
        const float wk = w[c0 + k];          // wave-uniform -> scalar load
        ps.x += v.x * wk; ps.y += v.y * wk;
        ps.z += v.z * wk; ps.w += v.w * wk;
    }
    reinterpret_cast<float4*>(partials + (size_t)vbid * NHW)[tid] = ps;

    __syncthreads();   // drains vmem: all partial stores complete before release
    if (tid == 0) {
        int prev = __hip_atomic_fetch_add(&score_done[b], 1, __ATOMIC_ACQ_REL, AGENT);
        s_last = (prev == NCHUNK - 1);
    }
    __syncthreads();

    if (s_last) {
        // last arriver merges 16 partials + softmax (bias dropped: shift-inv)
        const float4* pb = reinterpret_cast<const float4*>(
            partials + (size_t)b * NCHUNK * NHW);
        float4 s = {0.f, 0.f, 0.f, 0.f};
        #pragma unroll
        for (int i = 0; i < NCHUNK; ++i) {
            const float4 p = pb[i * (NHW / 4) + tid];
            s.x += p.x; s.y += p.y; s.z += p.z; s.w += p.w;
        }
        float m = fmaxf(fmaxf(s.x, s.y), fmaxf(s.z, s.w));
        m = wave_reduce_max(m);
        if (lane == 0) redm[wave] = m;
        __syncthreads();
        m = fmaxf(fmaxf(redm[0], redm[1]), fmaxf(redm[2], redm[3]));
        float4 e;
        e.x = __expf(s.x - m); e.y = __expf(s.y - m);
        e.z = __expf(s.z - m); e.w = __expf(s.w - m);
        float z = e.x + e.y + e.z + e.w;
        z = wave_reduce_sum(z);
        if (lane == 0) reds[wave] = z;
        __syncthreads();
        const float inv = 1.0f / (reds[0] + reds[1] + reds[2] + reds[3]);
        e.x *= inv; e.y *= inv; e.z *= inv; e.w *= inv;
        reinterpret_cast<float4*>(attn + (size_t)b * NHW)[tid] = e;
        __syncthreads();   // drain attn stores
        if (tid == 0)
            __hip_atomic_store(&flag[b], 1, __ATOMIC_RELEASE, AGENT);
    } else {
        if (tid == 0) {
            while (__hip_atomic_load(&flag[b], __ATOMIC_ACQUIRE, AGENT) == 0)
                __builtin_amdgcn_s_sleep(8);
        }
        __syncthreads();
    }

    // ---- pool phase: re-read slab (L3-hot), 16 channels per wave ----
    const float4* ar = reinterpret_cast<const float4*>(attn + (size_t)b * NHW);
    const float4 av0 = ar[4 * lane + 0];
    const float4 av1 = ar[4 * lane + 1];
    const float4 av2 = ar[4 * lane + 2];
    const float4 av3 = ar[4 * lane + 3];
    for (int cc = wave; cc < CCH; cc += 4) {
        const float4* xr = reinterpret_cast<const float4*>(
            x + ((size_t)(b * NC + c0 + cc)) * NHW);
        const float4 x0 = xr[4 * lane + 0];
        const float4 x1 = xr[4 * lane + 1];
        const float4 x2 = xr[4 * lane + 2];
        const float4 x3 = xr[4 * lane + 3];
        float acc = x0.x * av0.x + x0.y * av0.y + x0.z * av0.z + x0.w * av0.w
                  + x1.x * av1.x + x1.y * av1.y + x1.z * av1.z + x1.w * av1.w
                  + x2.x * av2.x + x2.y * av2.y + x2.z * av2.z + x2.w * av2.w
                  + x3.x * av3.x + x3.y * av3.y + x3.z * av3.z + x3.w * av3.w;
        acc = wave_reduce_sum(acc);
        if (lane == 0) out[b * NC + c0 + cc] = acc;
    }
}

extern "C" void kernel_launch(void* const* d_in, const int* in_sizes, int n_in,
                              void* d_out, int out_size, void* d_ws, size_t ws_size,
                              hipStream_t stream) {
    const float* x = (const float*)d_in[0];
    const float* w = (const float*)d_in[1];
    // d_in[2] (bias) irrelevant under softmax (shift-invariance).
    float* out      = (float*)d_out;
    float* partials = (float*)d_ws;                            // 4 MiB
    float* attn     = partials + (size_t)NB * NCHUNK * NHW;    // 256 KiB
    int*   ctrl     = (int*)(attn + (size_t)NB * NHW);         // 192 ints

    hipMemsetAsync(ctrl, 0, 192 * sizeof(int), stream);        // capture-legal
    fused_pipeline_kernel<<<NBLK, 256, 0, stream>>>(x, w, partials, attn,
                                                    ctrl, out);
}

// Round 6
// 113.257 us; speedup vs baseline: 3.0455x; 3.0455x over previous
//
#include <hip/hip_runtime.h>

// B=64, C=1024, HW=1024. x fp32 = 256 MiB = L3 capacity.
// R5 proved: batch-windowing cuts DRAM to ~265 MB (pool pass = L3 hits),
// but intra-kernel spin sync starved the machine (344us). R6 keeps the
// window, enforces it by STREAM-ORDERED LAUNCHES instead of spins:
//   4 groups of 16 batches; launch i runs scores(g_i) + softmax(g_{i-1})
//   + pool(g_{i-2}) as independent roles of one kernel. All dependencies
//   cross launch boundaries -> no atomics, no spin, deterministic.
// Reuse distance for pool(g): ~130 MiB < 256 MiB L3.
#define NB 64
#define NC 1024
#define NHW 1024
#define GRP 16                     // batches per group
#define NSCH 64                    // score chunks per batch
#define SCH (NC / NSCH)            // 16 channels per chunk
#define S_BLOCKS (GRP * NSCH)      // 1024
#define P_BLOCKS (GRP * (NC / 4))  // 4096 (4 channels per block, 1 per wave)
#define M_BLOCKS GRP               // 16

__device__ inline float wave_reduce_sum(float v) {
    #pragma unroll
    for (int off = 32; off; off >>= 1) v += __shfl_xor(v, off);
    return v;
}
__device__ inline float wave_reduce_max(float v) {
    #pragma unroll
    for (int off = 32; off; off >>= 1) v = fmaxf(v, __shfl_xor(v, off));
    return v;
}

__global__ __launch_bounds__(256) void stage_kernel(
        const float* __restrict__ x, const float* __restrict__ w,
        float* __restrict__ partials, float* __restrict__ attn,
        float* __restrict__ out, int sg, int pg, int mg, int nS, int nP) {
    __shared__ float redm[4], reds[4];
    const int tid  = threadIdx.x;
    const int wave = tid >> 6, lane = tid & 63;
    int bid = blockIdx.x;

    if (bid < nS) {
        // ---- scores role: stream 64 KiB contiguous slab (DRAM) ----
        const int b     = sg * GRP + (bid >> 6);
        const int chunk = bid & 63;
        const int c0    = chunk * SCH;
        const float* xb = x + ((size_t)(b * NC + c0)) * NHW + tid * 4;
        float4 ps = {0.f, 0.f, 0.f, 0.f};
        #pragma unroll
        for (int k = 0; k < SCH; ++k) {
            const float4 v = *reinterpret_cast<const float4*>(xb + (size_t)k * NHW);
            const float wk = w[c0 + k];          // wave-uniform -> scalar load
            ps.x += v.x * wk; ps.y += v.y * wk;
            ps.z += v.z * wk; ps.w += v.w * wk;
        }
        reinterpret_cast<float4*>(
            partials + ((size_t)b * NSCH + chunk) * NHW)[tid] = ps;
        return;
    }
    bid -= nS;
    if (bid < nP) {
        // ---- pool role: re-read x (L3-hot), wave-per-channel ----
        const int b = pg * GRP + (bid >> 8);
        const int c = (bid & 255) * 4 + wave;
        const float4* xr = reinterpret_cast<const float4*>(
            x + ((size_t)(b * NC + c)) * NHW);
        const float4* ar = reinterpret_cast<const float4*>(
            attn + (size_t)b * NHW);
        float acc = 0.f;
        #pragma unroll
        for (int q = 0; q < 4; ++q) {
            const float4 xv = xr[(q << 6) + lane];
            const float4 av = ar[(q << 6) + lane];
            acc += xv.x * av.x + xv.y * av.y + xv.z * av.z + xv.w * av.w;
        }
        acc = wave_reduce_sum(acc);
        if (lane == 0) out[b * NC + c] = acc;
        return;
    }
    bid -= nP;
    {
        // ---- softmax role: merge 64 partials, softmax, write attn ----
        const int b = mg * GRP + bid;
        const float4* pb = reinterpret_cast<const float4*>(
            partials + (size_t)b * NSCH * NHW);
        float4 s = {0.f, 0.f, 0.f, 0.f};
        #pragma unroll 8
        for (int k = 0; k < NSCH; ++k) {
            const float4 p = pb[k * (NHW / 4) + tid];
            s.x += p.x; s.y += p.y; s.z += p.z; s.w += p.w;
        }
        float m = fmaxf(fmaxf(s.x, s.y), fmaxf(s.z, s.w));
        m = wave_reduce_max(m);
        if (lane == 0) redm[wave] = m;
        __syncthreads();
        m = fmaxf(fmaxf(redm[0], redm[1]), fmaxf(redm[2], redm[3]));
        float4 e;
        e.x = __expf(s.x - m); e.y = __expf(s.y - m);
        e.z = __expf(s.z - m); e.w = __expf(s.w - m);
        float z = e.x + e.y + e.z + e.w;
        z = wave_reduce_sum(z);
        if (lane == 0) reds[wave] = z;
        __syncthreads();
        const float inv = 1.0f / (reds[0] + reds[1] + reds[2] + reds[3]);
        e.x *= inv; e.y *= inv; e.z *= inv; e.w *= inv;
        reinterpret_cast<float4*>(attn + (size_t)b * NHW)[tid] = e;
    }
}

extern "C" void kernel_launch(void* const* d_in, const int* in_sizes, int n_in,
                              void* d_out, int out_size, void* d_ws, size_t ws_size,
                              hipStream_t stream) {
    const float* x = (const float*)d_in[0];
    const float* w = (const float*)d_in[1];
    // d_in[2] (bias) irrelevant under softmax (shift-invariance).
    float* out      = (float*)d_out;
    float* partials = (float*)d_ws;                           // 16 MiB
    float* attn     = partials + (size_t)NB * NSCH * NHW;     // 256 KiB

    struct Step { int sg, pg, mg; };
    const Step steps[6] = {
        { 0, -1, -1},
        { 1, -1,  0},
        { 2,  0,  1},
        { 3,  1,  2},
        {-1,  2,  3},
        {-1,  3, -1},
    };
    for (int i = 0; i < 6; ++i) {
        const int nS = steps[i].sg >= 0 ? S_BLOCKS : 0;
        const int nP = steps[i].pg >= 0 ? P_BLOCKS : 0;
        const int nM = steps[i].mg >= 0 ? M_BLOCKS : 0;
        stage_kernel<<<nS + nP + nM, 256, 0, stream>>>(
            x, w, partials, attn, out,
            steps[i].sg, steps[i].pg, steps[i].mg, nS, nP);
    }
}